// Round 1
// baseline (96.458 us; speedup 1.0000x reference)
//
#include <hip/hip_runtime.h>
#include <hip/hip_bf16.h>
#include <stdint.h>

#define M_DIM 2048
#define N_DIM 4096
#define K_DIM 4096

#define BM 128
#define BN 128
#define BK 64

typedef __bf16 bf16x8 __attribute__((ext_vector_type(8)));
typedef float f32x4 __attribute__((ext_vector_type(4)));
typedef unsigned short ushort8_t __attribute__((ext_vector_type(8)));

__device__ __forceinline__ unsigned short f32_to_bf16_rne(float f) {
    union { float f; uint32_t u; } cvt;
    cvt.f = f;
    uint32_t u = cvt.u;
    uint32_t r = (u + 0x7fffu + ((u >> 16) & 1u)) >> 16;
    return (unsigned short)r;
}

__device__ __forceinline__ void gload_lds16(const void* g, void* l) {
    __builtin_amdgcn_global_load_lds(
        (__attribute__((address_space(1))) const void*)g,
        (__attribute__((address_space(3))) void*)l,
        16, 0, 0);
}

// ---------------------------------------------------------------------------
// x (f32 [M][K]) -> bf16 [M][K]
// ---------------------------------------------------------------------------
__global__ void convert_x_kernel(const float* __restrict__ x,
                                 unsigned short* __restrict__ xb, int n8) {
    int i = blockIdx.x * blockDim.x + threadIdx.x;
    int stride = gridDim.x * blockDim.x;
    for (; i < n8; i += stride) {
        const float4* p = (const float4*)(x + (size_t)i * 8);
        float4 v0 = p[0];
        float4 v1 = p[1];
        ushort8_t o;
        o[0] = f32_to_bf16_rne(v0.x);
        o[1] = f32_to_bf16_rne(v0.y);
        o[2] = f32_to_bf16_rne(v0.z);
        o[3] = f32_to_bf16_rne(v0.w);
        o[4] = f32_to_bf16_rne(v1.x);
        o[5] = f32_to_bf16_rne(v1.y);
        o[6] = f32_to_bf16_rne(v1.z);
        o[7] = f32_to_bf16_rne(v1.w);
        *(ushort8_t*)(xb + (size_t)i * 8) = o;
    }
}

// ---------------------------------------------------------------------------
// W (f32 [K][N]) -> Wt (bf16 [N][K])   tiled 64x64 transpose+convert
// ---------------------------------------------------------------------------
__global__ void transpose_convert_w(const float* __restrict__ W,
                                    unsigned short* __restrict__ Wt) {
    __shared__ float tile[64][65];  // +1 pad: store-side column reads are 2-way (free)
    const int k0 = blockIdx.y * 64;
    const int n0 = blockIdx.x * 64;
    const int t  = threadIdx.x;
    const int tx = t & 15;   // float4 index
    const int ty = t >> 4;   // 0..15

#pragma unroll
    for (int r = 0; r < 4; ++r) {
        int row = ty + 16 * r;  // k-local
        float4 v = *(const float4*)(W + (size_t)(k0 + row) * N_DIM + n0 + tx * 4);
        tile[row][tx * 4 + 0] = v.x;
        tile[row][tx * 4 + 1] = v.y;
        tile[row][tx * 4 + 2] = v.z;
        tile[row][tx * 4 + 3] = v.w;
    }
    __syncthreads();
#pragma unroll
    for (int r = 0; r < 4; ++r) {
        int nrow = ty + 16 * r;  // n-local
        ushort4 o;
        o.x = f32_to_bf16_rne(tile[tx * 4 + 0][nrow]);
        o.y = f32_to_bf16_rne(tile[tx * 4 + 1][nrow]);
        o.z = f32_to_bf16_rne(tile[tx * 4 + 2][nrow]);
        o.w = f32_to_bf16_rne(tile[tx * 4 + 3][nrow]);
        *(ushort4*)(Wt + (size_t)(n0 + nrow) * K_DIM + k0 + tx * 4) = o;
    }
}

// ---------------------------------------------------------------------------
// GEMM: C[m][n] = sum_k A[m][k] * Bt[n][k] + bias[n]
// A: bf16 [M][K], Bt: bf16 [N][K], C: f32 [M][N]
// m97 structure: 128x128 tile, BK=64, 4 waves (2x2), global_load_lds w=16,
// XOR-swizzled LDS (slot s = hi ^ (row&7)), 2 barriers / K-step.
// ---------------------------------------------------------------------------
__global__ __launch_bounds__(256, 3) void gemm_bf16(
    const unsigned short* __restrict__ A,
    const unsigned short* __restrict__ Bt,
    const float* __restrict__ bias,
    float* __restrict__ C) {
    __shared__ unsigned short sA[BM * BK];  // 16 KiB, swizzled 16B slots
    __shared__ unsigned short sB[BN * BK];  // 16 KiB

    const int t    = threadIdx.x;
    const int lane = t & 63;
    const int wave = t >> 6;
    const int wm   = wave >> 1;  // 0..1
    const int wn   = wave & 1;   // 0..1
    const int m0   = blockIdx.y * BM;
    const int n0   = blockIdx.x * BN;

    const int lrow = lane & 15;
    const int lhi  = lane >> 4;

    f32x4 acc[4][4];
#pragma unroll
    for (int i = 0; i < 4; ++i)
#pragma unroll
        for (int j = 0; j < 4; ++j) acc[i][j] = (f32x4)0.0f;

    for (int kt = 0; kt < K_DIM; kt += BK) {
        __syncthreads();  // previous compute done -> LDS reusable
        // stage: per tile 1024 chunks of 16B; chunk c: row=c>>3, phys slot s=c&3..7
        // logical k-chunk hi = s ^ (row&7)  (pre-swizzled global source, linear LDS dest)
#pragma unroll
        for (int i = 0; i < 4; ++i) {
            int c   = t + 256 * i;
            int row = c >> 3;
            int s   = c & 7;
            int hi  = s ^ (row & 7);
            gload_lds16(A + (size_t)(m0 + row) * K_DIM + kt + hi * 8,
                        (char*)sA + c * 16);
            gload_lds16(Bt + (size_t)(n0 + row) * K_DIM + kt + hi * 8,
                        (char*)sB + c * 16);
        }
        __syncthreads();  // vmcnt(0) drained by compiler before barrier

#pragma unroll
        for (int kk = 0; kk < 2; ++kk) {
            bf16x8 af[4], bf[4];
            const int hi = kk * 4 + lhi;
#pragma unroll
            for (int mi = 0; mi < 4; ++mi) {
                int row = wm * 64 + mi * 16 + lrow;
                int s   = hi ^ (row & 7);
                af[mi]  = *(const bf16x8*)&sA[row * BK + s * 8];
            }
#pragma unroll
            for (int nj = 0; nj < 4; ++nj) {
                int row = wn * 64 + nj * 16 + lrow;
                int s   = hi ^ (row & 7);
                bf[nj]  = *(const bf16x8*)&sB[row * BK + s * 8];
            }
#pragma unroll
            for (int mi = 0; mi < 4; ++mi)
#pragma unroll
                for (int nj = 0; nj < 4; ++nj)
                    acc[mi][nj] = __builtin_amdgcn_mfma_f32_16x16x32_bf16(
                        af[mi], bf[nj], acc[mi][nj], 0, 0, 0);
        }
    }

    // epilogue: C/D layout col=lane&15, row=(lane>>4)*4+reg  [HW-verified m89/m91]
#pragma unroll
    for (int nj = 0; nj < 4; ++nj) {
        int col  = n0 + wn * 64 + nj * 16 + lrow;
        float bv = bias[col];
#pragma unroll
        for (int mi = 0; mi < 4; ++mi) {
            int rbase = m0 + wm * 64 + mi * 16 + lhi * 4;
#pragma unroll
            for (int r = 0; r < 4; ++r) {
                C[(size_t)(rbase + r) * N_DIM + col] = acc[mi][nj][r] + bv;
            }
        }
    }
}

// ---------------------------------------------------------------------------
extern "C" void kernel_launch(void* const* d_in, const int* in_sizes, int n_in,
                              void* d_out, int out_size, void* d_ws, size_t ws_size,
                              hipStream_t stream) {
    const float* x    = (const float*)d_in[0];
    const float* w    = (const float*)d_in[1];
    const float* bias = (const float*)d_in[2];
    float* out        = (float*)d_out;

    unsigned short* xb = (unsigned short*)d_ws;                     // 16 MiB
    unsigned short* wt = (unsigned short*)((char*)d_ws +
                          (size_t)M_DIM * K_DIM * sizeof(unsigned short));  // 32 MiB

    // 1) x f32 -> bf16
    convert_x_kernel<<<2048, 256, 0, stream>>>(x, xb, M_DIM * K_DIM / 8);

    // 2) W f32 [K][N] -> Wt bf16 [N][K]
    dim3 tgrid(N_DIM / 64, K_DIM / 64);
    transpose_convert_w<<<tgrid, 256, 0, stream>>>(w, wt);

    // 3) GEMM + bias
    dim3 ggrid(N_DIM / BN, M_DIM / BM);
    gemm_bf16<<<ggrid, 256, 0, stream>>>(xb, wt, bias, out);
}